// Round 5
// baseline (681.758 us; speedup 1.0000x reference)
//
#include <hip/hip_runtime.h>

typedef __attribute__((ext_vector_type(8))) short short8;
typedef __attribute__((ext_vector_type(4))) float f32x4;

#define MFMA16(a,b,c) __builtin_amdgcn_mfma_f32_16x16x32_bf16((a),(b),(c),0,0,0)

constexpr int BHC = 32;     // B*H
constexpr int LEN = 8192;   // L
constexpr int DD  = 64;     // d
constexpr int RR  = 266;    // num_rows
constexpr int RP  = 272;    // 17*16
constexpr float EPSF = 1e-3f;

__device__ __forceinline__ unsigned short f2bf(float x) {   // RNE f32->bf16 bits
  unsigned u = __builtin_bit_cast(unsigned, x);
  return (unsigned short)((u + 0x7FFFu + ((u >> 16) & 1u)) >> 16);
}
__device__ __forceinline__ float bf2f(unsigned short h) {
  return __builtin_bit_cast(float, (unsigned)h << 16);
}
__device__ __forceinline__ void split2(float x, unsigned short& h, unsigned short& l) {
  h = f2bf(x);
  l = f2bf(x - bf2f(h));
}

// ---------------------------------------------------------------------------
// K1: grid (16, 32), 512 thr, 512 l-rows/block = 16 subtiles x 32.
//  phase A: feat = relu(K@P^T)+eps -> fT (P frags straight from global/L2)
//  phase B: KV^T += V^T@feat (V frags straight from global) + stage K(s+1)
// LDS: K 2x4608 + fT 2x21760 = 52736 B -> 2 blocks/CU if VGPR<=128
// ---------------------------------------------------------------------------
__global__ __launch_bounds__(512, 1) void perf_kv_kernel(
    const float* __restrict__ kin, const float* __restrict__ vin,
    const float* __restrict__ proj,
    float* __restrict__ kv_ws, float* __restrict__ ksum_ws)
{
  __shared__ unsigned short K_hi[32*72], K_lo[32*72];   // [l][d] pad 72
  __shared__ unsigned int fT_hi[RP*20], fT_lo[RP*20];   // [r][l-pair u32] pad 20

  const int t = threadIdx.x;
  const int wid = t >> 6, lane = t & 63, g = lane >> 4, ln = lane & 15;
  const int bh = blockIdx.y;
  const float* kb = kin + (size_t)bh*LEN*DD + (size_t)blockIdx.x*512*DD;
  const float* vb = vin + (size_t)bh*LEN*DD + (size_t)blockIdx.x*512*DD;

  const int nrt1 = (wid == 7) ? 3 : 2;                  // phase-A r-tiles {2w,2w+1,[w7]16}
  const int dt = wid & 3, rbase2 = (wid >> 2) * 9, nrt2 = (wid >> 2) ? 8 : 9;

  f32x4 kvacc[9];
#pragma unroll
  for (int j = 0; j < 9; ++j) kvacc[j] = (f32x4){0.f,0.f,0.f,0.f};
  float ksacc[3] = {0.f,0.f,0.f};

  const int sl = t >> 4, sc = t & 15;                   // staging map
  {   // stage subtile 0
    const float4 k4 = *(const float4*)&kb[(size_t)sl*DD + sc*4];
    unsigned short h0,q0,h1,q1,h2,q2,h3,q3;
    split2(k4.x,h0,q0); split2(k4.y,h1,q1); split2(k4.z,h2,q2); split2(k4.w,h3,q3);
    *(ushort4*)&K_hi[sl*72 + sc*4] = make_ushort4(h0,h1,h2,h3);
    *(ushort4*)&K_lo[sl*72 + sc*4] = make_ushort4(q0,q1,q2,q3);
  }
  __syncthreads();

  for (int s = 0; s < 16; ++s) {
    // ---- phase A ----
#pragma unroll
    for (int lt = 0; lt < 2; ++lt) {
      short8 KAh[2], KAl[2];
#pragma unroll
      for (int c = 0; c < 2; ++c) {
        KAh[c] = *(const short8*)&K_hi[(lt*16+ln)*72 + c*32 + g*8];
        KAl[c] = *(const short8*)&K_lo[(lt*16+ln)*72 + c*32 + g*8];
      }
#pragma unroll
      for (int j = 0; j < 3; ++j) {
        if (j >= nrt1) break;
        const int rt = (j == 2) ? 16 : 2*wid + j;
        const int r = rt*16 + ln;
        const bool rok = r < RR;
        short8 PBh[2], PBl[2];
#pragma unroll
        for (int c = 0; c < 2; ++c) {
          float pv[8];
          if (rok) {
            const float4 a = *(const float4*)&proj[r*DD + c*32 + g*8];
            const float4 b = *(const float4*)&proj[r*DD + c*32 + g*8 + 4];
            pv[0]=a.x; pv[1]=a.y; pv[2]=a.z; pv[3]=a.w;
            pv[4]=b.x; pv[5]=b.y; pv[6]=b.z; pv[7]=b.w;
          } else {
#pragma unroll
            for (int i2 = 0; i2 < 8; ++i2) pv[i2] = 0.f;
          }
#pragma unroll
          for (int i2 = 0; i2 < 8; ++i2) {
            unsigned short h, l2; split2(pv[i2], h, l2);
            PBh[c][i2] = (short)h; PBl[c][i2] = (short)l2;
          }
        }
        f32x4 a0 = {0.f,0.f,0.f,0.f}, a1 = a0, a2 = a0;   // 3 independent chains
#pragma unroll
        for (int c = 0; c < 2; ++c) {
          a0 = MFMA16(KAh[c], PBh[c], a0);
          a1 = MFMA16(KAh[c], PBl[c], a1);
          a2 = MFMA16(KAl[c], PBh[c], a2);
        }
        unsigned short h[4], q[4];
        float sum = 0.f;
#pragma unroll
        for (int reg = 0; reg < 4; ++reg) {
          const float fv = rok ? (fmaxf(a0[reg]+a1[reg]+a2[reg], 0.f) + EPSF) : 0.f;
          sum += fv;
          split2(fv, h[reg], q[reg]);
        }
        ksacc[j] += sum;
        *(uint2*)&fT_hi[r*20 + lt*8 + g*2] =
            make_uint2((unsigned)h[0]|((unsigned)h[1]<<16), (unsigned)h[2]|((unsigned)h[3]<<16));
        *(uint2*)&fT_lo[r*20 + lt*8 + g*2] =
            make_uint2((unsigned)q[0]|((unsigned)q[1]<<16), (unsigned)q[2]|((unsigned)q[3]<<16));
      }
    }
    __syncthreads();

    // ---- phase B: stage K(s+1) (K not read here) + V frags + MFMA2 ----
    if (s < 15) {
      const float4 k4 = *(const float4*)&kb[(size_t)((s+1)*32 + sl)*DD + sc*4];
      unsigned short h0,q0,h1,q1,h2,q2,h3,q3;
      split2(k4.x,h0,q0); split2(k4.y,h1,q1); split2(k4.z,h2,q2); split2(k4.w,h3,q3);
      *(ushort4*)&K_hi[sl*72 + sc*4] = make_ushort4(h0,h1,h2,h3);
      *(ushort4*)&K_lo[sl*72 + sc*4] = make_ushort4(q0,q1,q2,q3);
    }
    short8 VAh, VAl;                                    // V^T frag from global (L1/L2)
#pragma unroll
    for (int i = 0; i < 8; ++i) {
      const float v = vb[(size_t)(s*32 + g*8 + i)*DD + dt*16 + ln];
      unsigned short h, l2; split2(v, h, l2);
      VAh[i] = (short)h; VAl[i] = (short)l2;
    }
#pragma unroll
    for (int j = 0; j < 9; ++j) {                       // j's independent (ILP)
      if (j >= nrt2) break;
      const int rt = rbase2 + j;
      const short8 Bh = *(const short8*)&fT_hi[(rt*16+ln)*20 + g*4];
      const short8 Bl = *(const short8*)&fT_lo[(rt*16+ln)*20 + g*4];
      f32x4 a = kvacc[j];
      a = MFMA16(VAh, Bh, a);
      a = MFMA16(VAh, Bl, a);
      a = MFMA16(VAl, Bh, a);
      kvacc[j] = a;
    }
    __syncthreads();
  }

  // ---- epilogue ----
  float* kvb = kv_ws + (size_t)bh * DD * RP;
#pragma unroll
  for (int j = 0; j < 9; ++j) {
    if (j >= nrt2) break;
    const int rt = rbase2 + j;
#pragma unroll
    for (int reg = 0; reg < 4; ++reg)
      atomicAdd(&kvb[(dt*16 + g*4 + reg)*RP + rt*16 + ln], kvacc[j][reg]);
  }
#pragma unroll
  for (int j = 0; j < 3; ++j) {
    if (j >= nrt1) break;
    const int rt = (j == 2) ? 16 : 2*wid + j;
    float v = ksacc[j];
    v += __shfl_xor(v, 16);
    v += __shfl_xor(v, 32);
    if (lane < 16) atomicAdd(&ksum_ws[bh*RP + rt*16 + lane], v);
  }
}

// ---------------------------------------------------------------------------
// K2: grid (16, 32), 512 thr, 512 l-rows/block = 16 subtiles x 32.
//  phase A: feat_Q^T + den (P frags from global/L2, Q from LDS)
//  phase B: out = (feat@KV)/den (KV^T in regs) + stage Q(s+1) overlap
// LDS: Q 2x4608 + feat 2x18944 + ksum 1088 + den 256 = 48448 B
// ---------------------------------------------------------------------------
__global__ __launch_bounds__(512, 1) void perf_out_kernel(
    const float* __restrict__ qin, const float* __restrict__ proj,
    const float* __restrict__ kv_ws, const float* __restrict__ ksum_ws,
    float* __restrict__ out)
{
  __shared__ unsigned short Q_hi[32*72], Q_lo[32*72];
  __shared__ unsigned short feat_hi[32*296], feat_lo[32*296];  // [l][r] pad 296
  __shared__ float ksum_lds[RP];
  __shared__ float den_l[2][32];

  const int t = threadIdx.x;
  const int wid = t >> 6, lane = t & 63, g = lane >> 4, ln = lane & 15;
  const int bh = blockIdx.y;
  const float* qb = qin + (size_t)bh*LEN*DD + (size_t)blockIdx.x*512*DD;
  float* outb = out + (size_t)bh*LEN*DD + (size_t)blockIdx.x*512*DD;

  // prologue
  for (int idx = t; idx < 32*24; idx += 512) {          // zero feat pad cols 272..295
    const int row = idx / 24, c = 272 + idx % 24;
    feat_hi[row*296 + c] = 0; feat_lo[row*296 + c] = 0;
  }
  if (t < RP) ksum_lds[t] = ksum_ws[bh*RP + t];
  if (t < 32) den_l[0][t] = 0.f;

  const int sl = t >> 4, sc = t & 15;
  {   // stage Q subtile 0
    const float4 q4 = *(const float4*)&qb[(size_t)sl*DD + sc*4];
    unsigned short h0,q0,h1,q1,h2,q2,h3,q3;
    split2(q4.x,h0,q0); split2(q4.y,h1,q1); split2(q4.z,h2,q2); split2(q4.w,h3,q3);
    *(ushort4*)&Q_hi[sl*72 + sc*4] = make_ushort4(h0,h1,h2,h3);
    *(ushort4*)&Q_lo[sl*72 + sc*4] = make_ushort4(q0,q1,q2,q3);
  }

  // KV^T register fragments for this wave's dd-tile
  const int lt4 = wid >> 2, dt4 = wid & 3;
  short8 KVh[9], KVl[9];
  {
    const float* kvr = kv_ws + ((size_t)bh*DD + dt4*16 + ln) * RP;
#pragma unroll
    for (int kc = 0; kc < 9; ++kc) {
      const int r0 = kc*32 + g*8;
      float pv[8];
      if (r0 + 7 < RP) {
        const float4 a = *(const float4*)&kvr[r0];
        const float4 b = *(const float4*)&kvr[r0 + 4];
        pv[0]=a.x; pv[1]=a.y; pv[2]=a.z; pv[3]=a.w;
        pv[4]=b.x; pv[5]=b.y; pv[6]=b.z; pv[7]=b.w;
      } else {
#pragma unroll
        for (int i = 0; i < 8; ++i) pv[i] = 0.f;
      }
#pragma unroll
      for (int i = 0; i < 8; ++i) {
        unsigned short h, l2; split2(pv[i], h, l2);
        KVh[kc][i] = (short)h; KVl[kc][i] = (short)l2;
      }
    }
  }

  const int nrt1 = (wid >= 6) ? 3 : 2;   // r-tiles {2w,2w+1}; rt16: (w6,lt0),(w7,lt1)
  __syncthreads();

  for (int s = 0; s < 16; ++s) {
    // ---- phase A: feat + den ----
#pragma unroll
    for (int lt = 0; lt < 2; ++lt) {
      short8 QBh[2], QBl[2];
#pragma unroll
      for (int c = 0; c < 2; ++c) {
        QBh[c] = *(const short8*)&Q_hi[(lt*16+ln)*72 + c*32 + g*8];
        QBl[c] = *(const short8*)&Q_lo[(lt*16+ln)*72 + c*32 + g*8];
      }
#pragma unroll
      for (int j = 0; j < 3; ++j) {
        if (j >= nrt1) break;
        if (j == 2 && lt != (wid & 1)) continue;
        const int rt = (j == 2) ? 16 : 2*wid + j;
        const int ra = rt*16 + ln;                      // A-frag row
        const bool raok = ra < RR;
        short8 PAh[2], PAl[2];
#pragma unroll
        for (int c = 0; c < 2; ++c) {
          float pv[8];
          if (raok) {
            const float4 a = *(const float4*)&proj[ra*DD + c*32 + g*8];
            const float4 b = *(const float4*)&proj[ra*DD + c*32 + g*8 + 4];
            pv[0]=a.x; pv[1]=a.y; pv[2]=a.z; pv[3]=a.w;
            pv[4]=b.x; pv[5]=b.y; pv[6]=b.z; pv[7]=b.w;
          } else {
#pragma unroll
            for (int i2 = 0; i2 < 8; ++i2) pv[i2] = 0.f;
          }
#pragma unroll
          for (int i2 = 0; i2 < 8; ++i2) {
            unsigned short h, l2; split2(pv[i2], h, l2);
            PAh[c][i2] = (short)h; PAl[c][i2] = (short)l2;
          }
        }
        f32x4 a0 = {0.f,0.f,0.f,0.f}, a1 = a0, a2 = a0;
#pragma unroll
        for (int c = 0; c < 2; ++c) {
          a0 = MFMA16(PAh[c], QBh[c], a0);
          a1 = MFMA16(PAh[c], QBl[c], a1);
          a2 = MFMA16(PAl[c], QBh[c], a2);
        }
        // C-frag: row=r=rt*16+g*4+reg, col=l=lt*16+ln
        unsigned short h[4], q[4];
        float dacc = 0.f;
#pragma unroll
        for (int reg = 0; reg < 4; ++reg) {
          const int rr = rt*16 + g*4 + reg;
          const float fv = (rr < RR) ? (fmaxf(a0[reg]+a1[reg]+a2[reg], 0.f) + EPSF) : 0.f;
          dacc += fv * ksum_lds[rr];
          split2(fv, h[reg], q[reg]);
        }
        atomicAdd(&den_l[s & 1][lt*16 + ln], dacc);
        *(ushort4*)&feat_hi[(lt*16+ln)*296 + rt*16 + g*4] = make_ushort4(h[0],h[1],h[2],h[3]);
        *(ushort4*)&feat_lo[(lt*16+ln)*296 + rt*16 + g*4] = make_ushort4(q[0],q[1],q[2],q[3]);
      }
    }
    __syncthreads();

    // ---- phase B: GEMM4 + stage Q(s+1) + zero next den ----
    if (s < 15) {
      const float4 q4 = *(const float4*)&qb[(size_t)((s+1)*32 + sl)*DD + sc*4];
      unsigned short h0,q0,h1,q1,h2,q2,h3,q3;
      split2(q4.x,h0,q0); split2(q4.y,h1,q1); split2(q4.z,h2,q2); split2(q4.w,h3,q3);
      *(ushort4*)&Q_hi[sl*72 + sc*4] = make_ushort4(h0,h1,h2,h3);
      *(ushort4*)&Q_lo[sl*72 + sc*4] = make_ushort4(q0,q1,q2,q3);
    }
    if (t < 32) den_l[(s+1) & 1][t] = 0.f;
    f32x4 oacc0 = {0.f,0.f,0.f,0.f}, oacc1 = oacc0, oacc2 = oacc0;  // 3 chains of 9
#pragma unroll
    for (int kc = 0; kc < 9; ++kc) {
      const short8 Ah = *(const short8*)&feat_hi[(lt4*16+ln)*296 + kc*32 + g*8];
      const short8 Al = *(const short8*)&feat_lo[(lt4*16+ln)*296 + kc*32 + g*8];
      oacc0 = MFMA16(Ah, KVh[kc], oacc0);
      oacc1 = MFMA16(Ah, KVl[kc], oacc1);
      oacc2 = MFMA16(Al, KVh[kc], oacc2);
    }
#pragma unroll
    for (int reg = 0; reg < 4; ++reg) {
      const int l = lt4*16 + g*4 + reg;
      const float o = oacc0[reg] + oacc1[reg] + oacc2[reg];
      outb[(size_t)(s*32 + l)*DD + dt4*16 + ln] = o / den_l[s & 1][l];
    }
    __syncthreads();
  }
}

extern "C" void kernel_launch(void* const* d_in, const int* in_sizes, int n_in,
                              void* d_out, int out_size, void* d_ws, size_t ws_size,
                              hipStream_t stream) {
  (void)in_sizes; (void)n_in; (void)out_size; (void)ws_size;
  const float* q    = (const float*)d_in[0];
  const float* k    = (const float*)d_in[1];
  const float* v    = (const float*)d_in[2];
  const float* proj = (const float*)d_in[3];
  float* out     = (float*)d_out;
  float* kv_ws   = (float*)d_ws;                       // [32][64][272] = KV^T
  float* ksum_ws = kv_ws + (size_t)BHC * DD * RP;      // [32][272]

  size_t zbytes = ((size_t)BHC * DD * RP + (size_t)BHC * RP) * sizeof(float);
  hipMemsetAsync(d_ws, 0, zbytes, stream);

  perf_kv_kernel<<<dim3(16, BHC), dim3(512), 0, stream>>>(k, v, proj, kv_ws, ksum_ws);
  perf_out_kernel<<<dim3(16, BHC), dim3(512), 0, stream>>>(q, proj, kv_ws, ksum_ws, out);
}